// Round 14
// baseline (192.019 us; speedup 1.0000x reference)
//
#include <hip/hip_runtime.h>
#include <hip/hip_bf16.h>
#include <math.h>

// Problem constants: B=2, S=2048, E=1024, H=16, D=64, buckets 0..127 (causal => rel>=0)

typedef __attribute__((ext_vector_type(8))) short bf16x8;
typedef __attribute__((ext_vector_type(4))) float f32x4;

static __device__ __forceinline__ unsigned short f2bf(float x) {
    unsigned u = __float_as_uint(x);
    unsigned r = (u + 0x7fffu + ((u >> 16) & 1u)) >> 16;   // RNE
    return (unsigned short)r;
}
static __device__ __forceinline__ float bf2f(unsigned short h) {
    return __uint_as_float(((unsigned)h) << 16);
}
static __device__ __forceinline__ unsigned cvtpk(float lo, float hi) {
    unsigned r;
    asm("v_cvt_pk_bf16_f32 %0, %1, %2" : "=v"(r) : "v"(lo), "v"(hi));
    return r;   // D[15:0]=bf16(lo), D[31:16]=bf16(hi)
}
static __device__ __forceinline__ float fexp2(float x) {
    return __builtin_amdgcn_exp2f(x);
}

// async 16B global->LDS (HW uses wave-uniform LDS base + lane*16 -> dest must be linear)
#define GLOAD16(gp, lp)                                                            \
    __builtin_amdgcn_global_load_lds(                                              \
        (const __attribute__((address_space(1))) unsigned int*)(gp),               \
        (__attribute__((address_space(3))) unsigned int*)(lp), 16, 0, 0)

// ---------------- fused prep: x->bf16 | 4x W transpose->bf16 | relT ----------------
__global__ void prep(const float* __restrict__ x,
                     const float* __restrict__ W0, const float* __restrict__ W1,
                     const float* __restrict__ W2, const float* __restrict__ W3,
                     const float* __restrict__ rel,
                     unsigned short* __restrict__ xb,
                     unsigned short* __restrict__ T0, unsigned short* __restrict__ T1,
                     unsigned short* __restrict__ T2, unsigned short* __restrict__ T3,
                     unsigned short* __restrict__ relTb)
{
    __shared__ unsigned short tls[64][65];
    const int id  = blockIdx.x;
    const int tid = threadIdx.x;
    if (id < 2048) {                         // tobf16: x -> xb
        const size_t t = (size_t)id * 256 + tid;
        const float4* p = (const float4*)(x + t*8);
        float4 a = p[0], b = p[1];
        unsigned w0 = cvtpk(a.x, a.y), w1 = cvtpk(a.z, a.w);
        unsigned w2 = cvtpk(b.x, b.y), w3 = cvtpk(b.z, b.w);
        *(uint4*)(xb + t*8) = make_uint4(w0, w1, w2, w3);
    } else if (id < 3072) {                  // transp4
        const int local = id - 2048;
        const int z  = local >> 8;
        const float* W = (z == 0) ? W0 : (z == 1) ? W1 : (z == 2) ? W2 : W3;
        unsigned short* Wt = (z == 0) ? T0 : (z == 1) ? T1 : (z == 2) ? T2 : T3;
        const int bb  = local & 255;
        const int bxt = bb & 15;
        const int byt = bb >> 4;
        const int r   = tid >> 2;
        const int c0  = (tid & 3) * 16;
        const float* src = W + (size_t)(byt*64 + r)*1024 + bxt*64 + c0;
#pragma unroll
        for (int j = 0; j < 4; ++j) {
            float4 vv = ((const float4*)src)[j];
            tls[c0 + j*4 + 0][r] = f2bf(vv.x);
            tls[c0 + j*4 + 1][r] = f2bf(vv.y);
            tls[c0 + j*4 + 2][r] = f2bf(vv.z);
            tls[c0 + j*4 + 3][r] = f2bf(vv.w);
        }
        __syncthreads();
        unsigned short* dst = Wt + (size_t)(bxt*64 + r)*1024 + byt*64 + c0;
        unsigned w[8];
#pragma unroll
        for (int j = 0; j < 8; ++j)
            w[j] = (unsigned)tls[r][c0 + 2*j] | ((unsigned)tls[r][c0 + 2*j + 1] << 16);
        *(uint4*)(dst)     = make_uint4(w[0], w[1], w[2], w[3]);
        *(uint4*)(dst + 8) = make_uint4(w[4], w[5], w[6], w[7]);
    } else {                                 // relT: rel_emb -> [16][128][64] bf16
        const int t  = (id - 3072) * 256 + tid;
        const int d0 = (t & 7) * 8;
        const int n  = (t >> 3) & 127;
        const int h  = t >> 10;
        const float* src = rel + ((size_t)(n*16 + h))*64 + d0;
        float4 a = ((const float4*)src)[0], b = ((const float4*)src)[1];
        unsigned w0 = cvtpk(a.x, a.y), w1 = cvtpk(a.z, a.w);
        unsigned w2 = cvtpk(b.x, b.y), w3 = cvtpk(b.z, b.w);
        *(uint4*)(relTb + (size_t)h*8192 + n*64 + d0) = make_uint4(w0, w1, w2, w3);
    }
}

// ---------------- shared GEMM body macros (128x128 tile, BK=64, dbuf, gload_lds) ----------
#define GEMM_STAGE(t, buf)                                                             \
    {                                                                                  \
        const int k0s = (t) * 64;                                                      \
        _Pragma("unroll")                                                              \
        for (int j = 0; j < 4; ++j) {                                                  \
            GLOAD16(agp + (size_t)(j*32 + srow)*1024 + k0s, &Als[buf][0] + j*2048 + tid*8); \
            GLOAD16(bgp + (size_t)(j*32 + srow)*1024 + k0s, &Bls[buf][0] + j*2048 + tid*8); \
        }                                                                              \
    }

#define GEMM_COMPUTE(buf)                                                              \
    {                                                                                  \
        _Pragma("unroll")                                                              \
        for (int ks = 0; ks < 2; ++ks) {                                               \
            bf16x8 af[4], bfr[4];                                                      \
            _Pragma("unroll")                                                          \
            for (int m = 0; m < 4; ++m)                                                \
                af[m] = *(const bf16x8*)&Als[buf][(wr + m*16 + (lane & 15))*64 + ks*32 + (lane >> 4)*8]; \
            _Pragma("unroll")                                                          \
            for (int n = 0; n < 4; ++n)                                                \
                bfr[n] = *(const bf16x8*)&Bls[buf][(wc + n*16 + (lane & 15))*64 + ks*32 + (lane >> 4)*8]; \
            _Pragma("unroll")                                                          \
            for (int m = 0; m < 4; ++m)                                                \
                _Pragma("unroll")                                                      \
                for (int n = 0; n < 4; ++n)                                            \
                    acc[m][n] = __builtin_amdgcn_mfma_f32_16x16x32_bf16(af[m], bfr[n], acc[m][n], 0, 0, 0); \
        }                                                                              \
    }

// ---------------- fused QKV GEMM + RoPE: z=0 -> qb bf16 (pre-scaled by SCL); z=1 -> kb;
// z=2 -> vT bf16. RoPE fused in-register: pair (dd, dd+32) = acc[m][n], acc[m][n+2].
__global__ __launch_bounds__(256) void gemm_qkv(const unsigned short* __restrict__ A,
    const unsigned short* __restrict__ wtq, const unsigned short* __restrict__ wtk,
    const unsigned short* __restrict__ wtv,
    unsigned short* __restrict__ qb, unsigned short* __restrict__ kbb,
    unsigned short* __restrict__ vTb)
{
    __shared__ __align__(16) unsigned short Als[2][8192];
    __shared__ __align__(16) unsigned short Bls[2][8192];
    const int z = blockIdx.z;
    const unsigned short* Bt = (z == 0) ? wtq : (z == 1) ? wtk : wtv;

    const int tid  = threadIdx.x;
    const int wave = tid >> 6, lane = tid & 63;
    const int wr = (wave >> 1) * 64, wc = (wave & 1) * 64;
    const int bx = blockIdx.x, by = blockIdx.y;
    const int srow = tid >> 3;
    const unsigned short* agp = A  + (size_t)(by*128)*1024 + (tid & 7)*8;
    const unsigned short* bgp = Bt + (size_t)(bx*128)*1024 + (tid & 7)*8;

    f32x4 acc[4][4];
#pragma unroll
    for (int m = 0; m < 4; ++m)
#pragma unroll
        for (int n = 0; n < 4; ++n) acc[m][n] = (f32x4)0.f;

    GEMM_STAGE(0, 0);
    __syncthreads();
    int cur = 0;
    for (int t = 0; t < 16; ++t) {
        if (t < 15) GEMM_STAGE(t + 1, cur ^ 1);
        GEMM_COMPUTE(cur);
        __syncthreads();
        cur ^= 1;
    }

    if (z == 2) {
#pragma unroll
        for (int m = 0; m < 4; ++m) {
            const int r0 = by*128 + wr + m*16 + (lane >> 4)*4;
#pragma unroll
            for (int n = 0; n < 4; ++n) {
                const int col = bx*128 + wc + n*16 + (lane & 15);
                const int bb = r0 >> 11, ss = r0 & 2047;
                const int hh = col >> 6, dd = col & 63;
                unsigned r01 = cvtpk(acc[m][n][0], acc[m][n][1]);
                unsigned r23 = cvtpk(acc[m][n][2], acc[m][n][3]);
                *(uint2*)(vTb + (((size_t)bb*16 + hh)*64 + dd)*2048 + ss) = make_uint2(r01, r23);
            }
        }
    } else {
        unsigned short* O = z ? kbb : qb;
        const float CC = 0.41524101186092029f;   // log2(10000)/32
        const float qscl = z ? 1.0f : 0.1803368801111204f;   // (1/8)*log2(e) folded into q
#pragma unroll
        for (int n = 0; n < 2; ++n) {
            const int dd = n*16 + (lane & 15);   // < 32
            const float if0 = exp2f(-(float)(dd >> 1) * CC);
            const float if1 = exp2f(-(float)(16 + (dd >> 1)) * CC);
            const int col = bx*128 + wc + n*16 + (lane & 15);
            const int hh = col >> 6;
#pragma unroll
            for (int m = 0; m < 4; ++m) {
                const int r0 = by*128 + wr + m*16 + (lane >> 4)*4;
#pragma unroll
                for (int rg = 0; rg < 4; ++rg) {
                    const int row = r0 + rg;
                    const int bb = row >> 11, s = row & 2047;
                    const float x0 = acc[m][n][rg];
                    const float x1 = acc[m][n + 2][rg];
                    const float a0 = (float)s * if0;
                    const float a1 = (float)s * if1;
                    const float o0 = (x0 * __cosf(a0) - x1 * __sinf(a0)) * qscl;
                    const float o1 = (x1 * __cosf(a1) + x0 * __sinf(a1)) * qscl;
                    unsigned short* ob = O + (((size_t)bb*16 + hh)*2048 + s)*64 + dd;
                    ob[0]  = f2bf(o0);
                    ob[32] = f2bf(o1);
                }
            }
        }
    }
}

// ---------------- Wo GEMM: C fp32 row-major ----------------
__global__ __launch_bounds__(256) void gemm_o(const unsigned short* __restrict__ A,
                                              const unsigned short* __restrict__ Bt,
                                              float* __restrict__ C)
{
    __shared__ __align__(16) unsigned short Als[2][8192];
    __shared__ __align__(16) unsigned short Bls[2][8192];
    const int tid  = threadIdx.x;
    const int wave = tid >> 6, lane = tid & 63;
    const int wr = (wave >> 1) * 64, wc = (wave & 1) * 64;
    const int bx = blockIdx.x, by = blockIdx.y;
    const int srow = tid >> 3;
    const unsigned short* agp = A  + (size_t)(by*128)*1024 + (tid & 7)*8;
    const unsigned short* bgp = Bt + (size_t)(bx*128)*1024 + (tid & 7)*8;

    f32x4 acc[4][4];
#pragma unroll
    for (int m = 0; m < 4; ++m)
#pragma unroll
        for (int n = 0; n < 4; ++n) acc[m][n] = (f32x4)0.f;

    GEMM_STAGE(0, 0);
    __syncthreads();
    int cur = 0;
    for (int t = 0; t < 16; ++t) {
        if (t < 15) GEMM_STAGE(t + 1, cur ^ 1);
        GEMM_COMPUTE(cur);
        __syncthreads();
        cur ^= 1;
    }

#pragma unroll
    for (int m = 0; m < 4; ++m) {
        const int r0 = by*128 + wr + m*16 + (lane >> 4)*4;
#pragma unroll
        for (int n = 0; n < 4; ++n) {
            const int col = bx*128 + wc + n*16 + (lane & 15);
#pragma unroll
            for (int rg = 0; rg < 4; ++rg)
                C[(size_t)(r0 + rg)*1024 + col] = acc[m][n][rg];
        }
    }
}

// ---------------- qrel via MFMA (verified r10; q pre-scaled -> bias pre-scaled) ----------
__global__ __launch_bounds__(256) void qrel_mfma(const unsigned short* __restrict__ qb,
                                                 const unsigned short* __restrict__ relTb,
                                                 unsigned short* __restrict__ qrelb)
{
    __shared__ __align__(16) unsigned short Rls[8192];   // 128 buckets x 64
    __shared__ __align__(16) unsigned short Qls[8192];   // 128 s-rows  x 64
    const int tid  = threadIdx.x;
    const int wave = tid >> 6, lane = tid & 63;
    const int wr = (wave >> 1) * 64;     // bucket offset
    const int wc = (wave & 1) * 64;      // s offset
    const int s0 = blockIdx.x * 128;
    const int bh = blockIdx.y;
    const int h  = bh & 15;

    const unsigned short* qsrc = qb + ((size_t)bh*2048 + s0)*64;
    const unsigned short* rsrc = relTb + (size_t)h*8192;
#pragma unroll
    for (int j = 0; j < 4; ++j) {
        GLOAD16(rsrc + j*2048 + tid*8, &Rls[0] + j*2048 + tid*8);
        GLOAD16(qsrc + j*2048 + tid*8, &Qls[0] + j*2048 + tid*8);
    }

    f32x4 acc[4][4];
#pragma unroll
    for (int m = 0; m < 4; ++m)
#pragma unroll
        for (int n = 0; n < 4; ++n) acc[m][n] = (f32x4)0.f;

    __syncthreads();

#pragma unroll
    for (int ks = 0; ks < 2; ++ks) {
        bf16x8 rf[4], qf[4];
#pragma unroll
        for (int m = 0; m < 4; ++m)
            rf[m] = *(const bf16x8*)&Rls[(wr + m*16 + (lane & 15))*64 + ks*32 + (lane >> 4)*8];
#pragma unroll
        for (int n = 0; n < 4; ++n)
            qf[n] = *(const bf16x8*)&Qls[(wc + n*16 + (lane & 15))*64 + ks*32 + (lane >> 4)*8];
#pragma unroll
        for (int m = 0; m < 4; ++m)
#pragma unroll
            for (int n = 0; n < 4; ++n)
                acc[m][n] = __builtin_amdgcn_mfma_f32_16x16x32_bf16(rf[m], qf[n], acc[m][n], 0, 0, 0);
    }

#pragma unroll
    for (int m = 0; m < 4; ++m) {
        const int bkt0 = wr + m*16 + (lane >> 4)*4;
#pragma unroll
        for (int n = 0; n < 4; ++n) {
            const int srow = s0 + wc + n*16 + (lane & 15);
            unsigned r01 = cvtpk(acc[m][n][0], acc[m][n][1]);
            unsigned r23 = cvtpk(acc[m][n][2], acc[m][n][3]);
            *(uint2*)(qrelb + ((size_t)bh*2048 + srow)*128 + bkt0) = make_uint2(r01, r23);
        }
    }
}

// ---------------- MFMA causal flash attention, 64-key tiles, dbuf, lean softmax ----------
// 512 blocks; block (bh, px) runs q-tiles px and 31-px. Far tiles (t<bxc): rel>=1
// guaranteed -> no mask/clamp. Bucket via u16 byte-offset table (no per-pair log2).
// Scores pre-scaled (q carries SCL) -> sv = s + bias.
__global__ __launch_bounds__(256) void flash_mfma(
    const unsigned short* __restrict__ qb, const unsigned short* __restrict__ kb,
    const unsigned short* __restrict__ vT, const unsigned short* __restrict__ qrelb,
    unsigned short* __restrict__ ctxb)
{
    __shared__ __align__(16) unsigned short kls[2][4096];   // [buf][64 keys x 64 d] swizzled
    __shared__ __align__(16) unsigned short vtls[2][4096];  // [buf][64 d x 64 keys] swizzled
    __shared__ __align__(16) unsigned short qrels[64*136];
    __shared__ unsigned short btbl[2048];                   // bucket(rel)*2 (byte offset)

    const int tid = threadIdx.x;
    const int id  = blockIdx.x;                // 0..511
    const int bh  = id & 31;                   // head -> XCD locality
    const int px  = id >> 5;                   // 0..15 -> pair (px, 31-px)

    const int w   = tid >> 6;
    const int l   = tid & 63;
    const int q15 = l & 15;
    const int g   = l >> 4;

    // bucket byte-offset table (once per block; first-pass barrier covers visibility)
    for (int idx = tid; idx < 2048; idx += 256) {
        int bkt;
        if (idx < 64) bkt = idx;
        else {
            bkt = 64 + (int)(__log2f((float)idx) * 8.0f - 48.0f);
            bkt = bkt > 127 ? 127 : bkt;
        }
        btbl[idx] = (unsigned short)(bkt * 2);
    }

    // staging setup: waves 0,1 -> K, waves 2,3 -> V^T; 4 GLOAD16/thread/tile
    const size_t headoff = (size_t)bh * 2048 * 64;
    const unsigned short* gbase;
    int jstride;
    if (tid < 128) { gbase = kb + headoff; jstride = 64; }
    else           { gbase = vT + headoff; jstride = 1;  }
    int soff[4], doff[4];
#pragma unroll
    for (int i = 0; i < 4; ++i) {
        const int D = (tid & 127)*16 + i*2048;
        const int r = D >> 7, c = (D >> 4) & 7;
        soff[i] = (tid < 128) ? (r*64 + ((c ^ (r & 7))*8))
                              : (r*2048 + ((c ^ (r & 7))*8));
        doff[i] = D;
    }

    const char* qrow_base = (const char*)qrels + (w*16 + q15) * 272;  // 136 u16 = 272 B
    const int srcA = ((2*g) & 3)*16 + q15;
    const int srcB = ((2*g + 1) & 3)*16 + q15;

    int cur = 0;
    for (int pp = 0; pp < 2; ++pp) {
        const int bxc = pp ? (31 - px) : px;
        const int i0  = bxc * 64;
        const int iq  = i0 + w*16 + q15;

        __syncthreads();                        // prev pass fully done
        for (int idx = tid; idx < 1024; idx += 256) {
            const int r = idx >> 4, c8 = idx & 15;
            uint4 vv = *(const uint4*)(qrelb + ((size_t)bh*2048 + i0 + r)*128 + c8*8);
            *(uint4*)&qrels[r*136 + c8*8] = vv;
        }
        {   // prefetch tile 0 into buf cur
            char* lb = (tid < 128) ? (char*)kls[cur] : (char*)vtls[cur];
#pragma unroll
            for (int i = 0; i < 4; ++i) GLOAD16(gbase + soff[i], lb + doff[i]);
        }

        bf16x8 qf0, qf1;
        {
            const unsigned short* qrow = qb + ((size_t)bh*2048 + i0 + w*16 + q15)*64;
            qf0 = *(const bf16x8*)(qrow + g*8);
            qf1 = *(const bf16x8*)(qrow + 32 + g*8);
        }

        f32x4 acc[4];
#pragma unroll
        for (int d = 0; d < 4; ++d) acc[d] = (f32x4)0.f;
        float mrun = -INFINITY, lsum = 0.f;

        __syncthreads();                        // qrels+btbl staged + tile0 drained

        const int ntiles = bxc + 1;
        for (int t = 0; t < ntiles; ++t) {
            const int j0 = t * 64;
            if (t + 1 < ntiles) {               // prefetch t+1 into other buf
                const unsigned short* gt = gbase + (size_t)(j0 + 64) * jstride;
                char* lb = (tid < 128) ? (char*)kls[cur ^ 1] : (char*)vtls[cur ^ 1];
#pragma unroll
                for (int i = 0; i < 4; ++i) GLOAD16(gt + soff[i], lb + doff[i]);
            }

            // swapped QK^T: 4 key-subtiles of 16
            f32x4 s[4];
#pragma unroll
            for (int ss = 0; ss < 4; ++ss) s[ss] = (f32x4)0.f;
#pragma unroll
            for (int ks = 0; ks < 2; ++ks) {
                const bf16x8 qq = ks ? qf1 : qf0;
                const int gr = ((ks*4 + g) ^ (q15 & 7)) * 8;
#pragma unroll
                for (int ss = 0; ss < 4; ++ss) {
                    bf16x8 kf = *(const bf16x8*)&kls[cur][(ss*16 + q15)*64 + gr];
                    s[ss] = __builtin_amdgcn_mfma_f32_16x16x32_bf16(kf, qq, s[ss], 0, 0, 0);
                }
            }

            // lean softmax input: far tiles have rel>=1 (no mask/clamp)
            const int relbase = iq - j0 - g*4;   // rel = relbase - ss*16 - r
            float sv[16];
            float tmax = -INFINITY;
            if (t != bxc) {
#pragma unroll
                for (int ss = 0; ss < 4; ++ss) {
#pragma unroll
                    for (int r = 0; r < 4; ++r) {
                        const int bi = relbase - ss*16 - r;
                        const float bias = bf2f(*(const unsigned short*)(qrow_base + btbl[bi]));
                        const float val = s[ss][r] + bias;
                        sv[ss*4 + r] = val;
                        tmax = fmaxf(tmax, val);
                    }
                }
            } else {
#pragma unroll
                for (int ss = 0; ss < 4; ++ss) {
#pragma unroll
                    for (int r = 0; r < 4; ++r) {
                        const int rel = relbase - ss*16 - r;
                        const int bi = rel < 0 ? 0 : rel;
                        const float bias = bf2f(*(const unsigned short*)(qrow_base + btbl[bi]));
                        float val = s[ss][r] + bias;
                        val = (rel >= 0) ? val : -1e30f;
                        sv[ss*4 + r] = val;
                        tmax = fmaxf(tmax, val);
                    }
                }
            }
            tmax = fmaxf(tmax, __shfl_xor(tmax, 16));
            tmax = fmaxf(tmax, __shfl_xor(tmax, 32));

            // defer-max: skip rescale when all columns grew <= 8
            float newm = mrun;
            if (!__all(tmax - mrun <= 8.0f)) {
                newm = fmaxf(mrun, tmax);
                const float corr = fexp2(mrun - newm);
                lsum *= corr;
#pragma unroll
                for (int d = 0; d < 4; ++d) {
                    acc[d][0] *= corr; acc[d][1] *= corr; acc[d][2] *= corr; acc[d][3] *= corr;
                }
                mrun = newm;
            }

            float p[16], ps = 0.f;
#pragma unroll
            for (int j = 0; j < 16; ++j) { p[j] = fexp2(sv[j] - newm); ps += p[j]; }
            ps += __shfl_xor(ps, 16);
            ps += __shfl_xor(ps, 32);
            lsum += ps;

            // two 32-key chunks: build P^T B-frag via cvt_pk + shuffles, then PV
#pragma unroll
            for (int ck = 0; ck < 2; ++ck) {
                unsigned w00 = cvtpk(p[8*ck+0], p[8*ck+1]);
                unsigned w01 = cvtpk(p[8*ck+2], p[8*ck+3]);
                unsigned w10 = cvtpk(p[8*ck+4], p[8*ck+5]);
                unsigned w11 = cvtpk(p[8*ck+6], p[8*ck+7]);
                unsigned a0 = (unsigned)__shfl((int)w00, srcA);
                unsigned b0 = (unsigned)__shfl((int)w10, srcA);
                unsigned a1 = (unsigned)__shfl((int)w01, srcA);
                unsigned b1 = (unsigned)__shfl((int)w11, srcA);
                unsigned a2 = (unsigned)__shfl((int)w00, srcB);
                unsigned b2 = (unsigned)__shfl((int)w10, srcB);
                unsigned a3 = (unsigned)__shfl((int)w01, srcB);
                unsigned b3 = (unsigned)__shfl((int)w11, srcB);
                union { unsigned u[4]; bf16x8 v; } pu;
                pu.u[0] = (g < 2) ? a0 : b0;
                pu.u[1] = (g < 2) ? a1 : b1;
                pu.u[2] = (g < 2) ? a2 : b2;
                pu.u[3] = (g < 2) ? a3 : b3;
#pragma unroll
                for (int dblk = 0; dblk < 4; ++dblk) {
                    const int d2 = dblk*16 + q15;
                    bf16x8 vf = *(const bf16x8*)&vtls[cur][d2*64 + (((ck*4 + g) ^ (d2 & 7))*8)];
                    acc[dblk] = __builtin_amdgcn_mfma_f32_16x16x32_bf16(vf, pu.v, acc[dblk], 0, 0, 0);
                }
            }

            __syncthreads();                    // drains t+1 loads; all waves done with buf cur
            cur ^= 1;
        }

        const float inv = 1.0f / lsum;
        const int s2 = i0 + w*16 + q15;
        const int b2 = bh >> 4, hh = bh & 15;
        unsigned short* obase = ctxb + (((size_t)b2*2048 + s2)*16 + hh)*64;
#pragma unroll
        for (int dblk = 0; dblk < 4; ++dblk) {
            const int d0 = dblk*16 + g*4;
            unsigned r01 = cvtpk(acc[dblk][0]*inv, acc[dblk][1]*inv);
            unsigned r23 = cvtpk(acc[dblk][2]*inv, acc[dblk][3]*inv);
            *(uint2*)(obase + d0) = make_uint2(r01, r23);
        }
    }
}

extern "C" void kernel_launch(void* const* d_in, const int* in_sizes, int n_in,
                              void* d_out, int out_size, void* d_ws, size_t ws_size,
                              hipStream_t stream)
{
    const float* x   = (const float*)d_in[0];
    const float* Wq  = (const float*)d_in[1];
    const float* Wk  = (const float*)d_in[2];
    const float* Wv  = (const float*)d_in[3];
    const float* Wo  = (const float*)d_in[4];
    const float* rel = (const float*)d_in[5];

    float* ws = (float*)d_ws;
    unsigned short* qb    = (unsigned short*)(ws + 8388608);    // 4,194,304 bf16
    unsigned short* kbb   = (unsigned short*)(ws + 10485760);   // 4,194,304 bf16
    unsigned short* qrelb = (unsigned short*)(ws + 12582912);   // 8,388,608 bf16 (4M floats)
    unsigned short* vTb   = (unsigned short*)(ws + 16777216);   // 4,194,304 bf16
    unsigned short* xb    = (unsigned short*)(ws + 18874368);   // 4,194,304 bf16
    unsigned short* wtq   = (unsigned short*)(ws + 20971520);   // 1,048,576 bf16 each
    unsigned short* wtk   = (unsigned short*)(ws + 21495808);
    unsigned short* wtv   = (unsigned short*)(ws + 22020096);
    unsigned short* wto   = (unsigned short*)(ws + 22544384);
    unsigned short* relTb = (unsigned short*)(ws + 23068672);   // 131,072 bf16
    unsigned short* ctxb  = (unsigned short*)ws;                // first region (free)

    prep<<<3136, 256, 0, stream>>>(x, Wq, Wk, Wv, Wo, rel, xb, wtq, wtk, wtv, wto, relTb);
    gemm_qkv<<<dim3(8, 32, 3), 256, 0, stream>>>(xb, wtq, wtk, wtv, qb, kbb, vTb);
    qrel_mfma<<<dim3(16, 32), 256, 0, stream>>>(qb, relTb, qrelb);
    flash_mfma<<<512, 256, 0, stream>>>(qb, kbb, vTb, qrelb, ctxb);
    gemm_o<<<dim3(8, 32), 256, 0, stream>>>(ctxb, wto, (float*)d_out);
}

// Round 15
// 185.112 us; speedup vs baseline: 1.0373x; 1.0373x over previous
//
#include <hip/hip_runtime.h>
#include <hip/hip_bf16.h>
#include <math.h>

// Problem constants: B=2, S=2048, E=1024, H=16, D=64, buckets 0..127 (causal => rel>=0)

typedef __attribute__((ext_vector_type(8))) short bf16x8;
typedef __attribute__((ext_vector_type(4))) float f32x4;

static __device__ __forceinline__ unsigned short f2bf(float x) {
    unsigned u = __float_as_uint(x);
    unsigned r = (u + 0x7fffu + ((u >> 16) & 1u)) >> 16;   // RNE
    return (unsigned short)r;
}
static __device__ __forceinline__ float bf2f(unsigned short h) {
    return __uint_as_float(((unsigned)h) << 16);
}
static __device__ __forceinline__ unsigned cvtpk(float lo, float hi) {
    unsigned r;
    asm("v_cvt_pk_bf16_f32 %0, %1, %2" : "=v"(r) : "v"(lo), "v"(hi));
    return r;
}
static __device__ __forceinline__ float fexp2(float x) {
    return __builtin_amdgcn_exp2f(x);
}

// async 16B global->LDS (wave-uniform LDS base + lane*16 -> dest must be linear)
#define GLOAD16(gp, lp)                                                            \
    __builtin_amdgcn_global_load_lds(                                              \
        (const __attribute__((address_space(1))) unsigned int*)(gp),               \
        (__attribute__((address_space(3))) unsigned int*)(lp), 16, 0, 0)

// ---------------- fused prep: x->bf16 | 4x W transpose | relT | rope cos/sin table --------
__global__ void prep(const float* __restrict__ x,
                     const float* __restrict__ W0, const float* __restrict__ W1,
                     const float* __restrict__ W2, const float* __restrict__ W3,
                     const float* __restrict__ rel,
                     unsigned short* __restrict__ xb,
                     unsigned short* __restrict__ T0, unsigned short* __restrict__ T1,
                     unsigned short* __restrict__ T2, unsigned short* __restrict__ T3,
                     unsigned short* __restrict__ relTb, float* __restrict__ ropeT)
{
    __shared__ unsigned short tls[64][65];
    const int id  = blockIdx.x;
    const int tid = threadIdx.x;
    if (id < 2048) {                         // tobf16: x -> xb
        const size_t t = (size_t)id * 256 + tid;
        const float4* p = (const float4*)(x + t*8);
        float4 a = p[0], b = p[1];
        unsigned w0 = cvtpk(a.x, a.y), w1 = cvtpk(a.z, a.w);
        unsigned w2 = cvtpk(b.x, b.y), w3 = cvtpk(b.z, b.w);
        *(uint4*)(xb + t*8) = make_uint4(w0, w1, w2, w3);
    } else if (id < 3072) {                  // transp4
        const int local = id - 2048;
        const int z  = local >> 8;
        const float* W = (z == 0) ? W0 : (z == 1) ? W1 : (z == 2) ? W2 : W3;
        unsigned short* Wt = (z == 0) ? T0 : (z == 1) ? T1 : (z == 2) ? T2 : T3;
        const int bb  = local & 255;
        const int bxt = bb & 15;
        const int byt = bb >> 4;
        const int r   = tid >> 2;
        const int c0  = (tid & 3) * 16;
        const float* src = W + (size_t)(byt*64 + r)*1024 + bxt*64 + c0;
#pragma unroll
        for (int j = 0; j < 4; ++j) {
            float4 vv = ((const float4*)src)[j];
            tls[c0 + j*4 + 0][r] = f2bf(vv.x);
            tls[c0 + j*4 + 1][r] = f2bf(vv.y);
            tls[c0 + j*4 + 2][r] = f2bf(vv.z);
            tls[c0 + j*4 + 3][r] = f2bf(vv.w);
        }
        __syncthreads();
        unsigned short* dst = Wt + (size_t)(bxt*64 + r)*1024 + byt*64 + c0;
        unsigned w[8];
#pragma unroll
        for (int j = 0; j < 8; ++j)
            w[j] = (unsigned)tls[r][c0 + 2*j] | ((unsigned)tls[r][c0 + 2*j + 1] << 16);
        *(uint4*)(dst)     = make_uint4(w[0], w[1], w[2], w[3]);
        *(uint4*)(dst + 8) = make_uint4(w[4], w[5], w[6], w[7]);
    } else if (id < 3136) {                  // relT: rel_emb -> [16][128][64] bf16
        const int t  = (id - 3072) * 256 + tid;
        const int d0 = (t & 7) * 8;
        const int n  = (t >> 3) & 127;
        const int h  = t >> 10;
        const float* src = rel + ((size_t)(n*16 + h))*64 + d0;
        float4 a = ((const float4*)src)[0], b = ((const float4*)src)[1];
        unsigned w0 = cvtpk(a.x, a.y), w1 = cvtpk(a.z, a.w);
        unsigned w2 = cvtpk(b.x, b.y), w3 = cvtpk(b.z, b.w);
        *(uint4*)(relTb + (size_t)h*8192 + n*64 + d0) = make_uint4(w0, w1, w2, w3);
    } else {                                 // rope table [2048 s][16 f][cos0,sin0,cos1,sin1]
        const int idx = (id - 3136) * 256 + tid;     // 0..32767
        const int s = idx >> 4, f = idx & 15;
        const float CC = 0.41524101186092029f;       // log2(10000)/32
        const float if0 = exp2f(-(float)f * CC);
        const float if1 = exp2f(-(float)(f + 16) * CC);
        const float a0 = (float)s * if0;
        const float a1 = (float)s * if1;
        *(float4*)(ropeT + (size_t)idx*4) =
            make_float4(__cosf(a0), __sinf(a0), __cosf(a1), __sinf(a1));
    }
}

// ---------------- shared GEMM body macros (128x128 tile, BK=64, dbuf, gload_lds) ----------
#define GEMM_STAGE(t, buf)                                                             \
    {                                                                                  \
        const int k0s = (t) * 64;                                                      \
        _Pragma("unroll")                                                              \
        for (int j = 0; j < 4; ++j) {                                                  \
            GLOAD16(agp + (size_t)(j*32 + srow)*1024 + k0s, &Als[buf][0] + j*2048 + tid*8); \
            GLOAD16(bgp + (size_t)(j*32 + srow)*1024 + k0s, &Bls[buf][0] + j*2048 + tid*8); \
        }                                                                              \
    }

#define GEMM_COMPUTE(buf)                                                              \
    {                                                                                  \
        _Pragma("unroll")                                                              \
        for (int ks = 0; ks < 2; ++ks) {                                               \
            bf16x8 af[4], bfr[4];                                                      \
            _Pragma("unroll")                                                          \
            for (int m = 0; m < 4; ++m)                                                \
                af[m] = *(const bf16x8*)&Als[buf][(wr + m*16 + (lane & 15))*64 + ks*32 + (lane >> 4)*8]; \
            _Pragma("unroll")                                                          \
            for (int n = 0; n < 4; ++n)                                                \
                bfr[n] = *(const bf16x8*)&Bls[buf][(wc + n*16 + (lane & 15))*64 + ks*32 + (lane >> 4)*8]; \
            _Pragma("unroll")                                                          \
            for (int m = 0; m < 4; ++m)                                                \
                _Pragma("unroll")                                                      \
                for (int n = 0; n < 4; ++n)                                            \
                    acc[m][n] = __builtin_amdgcn_mfma_f32_16x16x32_bf16(af[m], bfr[n], acc[m][n], 0, 0, 0); \
        }                                                                              \
    }

// ---------------- fused QKV GEMM + RoPE (table-driven): z=0 -> qb (pre-scaled); z=1 -> kb;
// z=2 -> vT bf16 ----
__global__ __launch_bounds__(256) void gemm_qkv(const unsigned short* __restrict__ A,
    const unsigned short* __restrict__ wtq, const unsigned short* __restrict__ wtk,
    const unsigned short* __restrict__ wtv, const float* __restrict__ ropeT,
    unsigned short* __restrict__ qb, unsigned short* __restrict__ kbb,
    unsigned short* __restrict__ vTb)
{
    __shared__ __align__(16) unsigned short Als[2][8192];
    __shared__ __align__(16) unsigned short Bls[2][8192];
    const int z = blockIdx.z;
    const unsigned short* Bt = (z == 0) ? wtq : (z == 1) ? wtk : wtv;

    const int tid  = threadIdx.x;
    const int wave = tid >> 6, lane = tid & 63;
    const int wr = (wave >> 1) * 64, wc = (wave & 1) * 64;
    const int bx = blockIdx.x, by = blockIdx.y;
    const int srow = tid >> 3;
    const unsigned short* agp = A  + (size_t)(by*128)*1024 + (tid & 7)*8;
    const unsigned short* bgp = Bt + (size_t)(bx*128)*1024 + (tid & 7)*8;

    f32x4 acc[4][4];
#pragma unroll
    for (int m = 0; m < 4; ++m)
#pragma unroll
        for (int n = 0; n < 4; ++n) acc[m][n] = (f32x4)0.f;

    GEMM_STAGE(0, 0);
    __syncthreads();
    int cur = 0;
    for (int t = 0; t < 16; ++t) {
        if (t < 15) GEMM_STAGE(t + 1, cur ^ 1);
        GEMM_COMPUTE(cur);
        __syncthreads();
        cur ^= 1;
    }

    if (z == 2) {
#pragma unroll
        for (int m = 0; m < 4; ++m) {
            const int r0 = by*128 + wr + m*16 + (lane >> 4)*4;
#pragma unroll
            for (int n = 0; n < 4; ++n) {
                const int col = bx*128 + wc + n*16 + (lane & 15);
                const int bb = r0 >> 11, ss = r0 & 2047;
                const int hh = col >> 6, dd = col & 63;
                unsigned r01 = cvtpk(acc[m][n][0], acc[m][n][1]);
                unsigned r23 = cvtpk(acc[m][n][2], acc[m][n][3]);
                *(uint2*)(vTb + (((size_t)bb*16 + hh)*64 + dd)*2048 + ss) = make_uint2(r01, r23);
            }
        }
    } else {
        unsigned short* O = z ? kbb : qb;
        const float qscl = z ? 1.0f : 0.1803368801111204f;   // (1/8)*log2(e) folded into q
#pragma unroll
        for (int n = 0; n < 2; ++n) {
            const int dd = n*16 + (lane & 15);   // < 32
            const int f  = dd >> 1;
            const int col = bx*128 + wc + n*16 + (lane & 15);
            const int hh = col >> 6;
#pragma unroll
            for (int m = 0; m < 4; ++m) {
                const int r0 = by*128 + wr + m*16 + (lane >> 4)*4;
#pragma unroll
                for (int rg = 0; rg < 4; ++rg) {
                    const int row = r0 + rg;
                    const int bb = row >> 11, s = row & 2047;
                    const float4 cs = *(const float4*)(ropeT + ((size_t)(s*16 + f))*4);
                    const float x0 = acc[m][n][rg];
                    const float x1 = acc[m][n + 2][rg];
                    const float o0 = (x0 * cs.x - x1 * cs.y) * qscl;
                    const float o1 = (x1 * cs.z + x0 * cs.w) * qscl;
                    unsigned short* ob = O + (((size_t)bb*16 + hh)*2048 + s)*64 + dd;
                    ob[0]  = f2bf(o0);
                    ob[32] = f2bf(o1);
                }
            }
        }
    }
}

// ---------------- Wo GEMM: C fp32 row-major ----------------
__global__ __launch_bounds__(256) void gemm_o(const unsigned short* __restrict__ A,
                                              const unsigned short* __restrict__ Bt,
                                              float* __restrict__ C)
{
    __shared__ __align__(16) unsigned short Als[2][8192];
    __shared__ __align__(16) unsigned short Bls[2][8192];
    const int tid  = threadIdx.x;
    const int wave = tid >> 6, lane = tid & 63;
    const int wr = (wave >> 1) * 64, wc = (wave & 1) * 64;
    const int bx = blockIdx.x, by = blockIdx.y;
    const int srow = tid >> 3;
    const unsigned short* agp = A  + (size_t)(by*128)*1024 + (tid & 7)*8;
    const unsigned short* bgp = Bt + (size_t)(bx*128)*1024 + (tid & 7)*8;

    f32x4 acc[4][4];
#pragma unroll
    for (int m = 0; m < 4; ++m)
#pragma unroll
        for (int n = 0; n < 4; ++n) acc[m][n] = (f32x4)0.f;

    GEMM_STAGE(0, 0);
    __syncthreads();
    int cur = 0;
    for (int t = 0; t < 16; ++t) {
        if (t < 15) GEMM_STAGE(t + 1, cur ^ 1);
        GEMM_COMPUTE(cur);
        __syncthreads();
        cur ^= 1;
    }

#pragma unroll
    for (int m = 0; m < 4; ++m) {
        const int r0 = by*128 + wr + m*16 + (lane >> 4)*4;
#pragma unroll
        for (int n = 0; n < 4; ++n) {
            const int col = bx*128 + wc + n*16 + (lane & 15);
#pragma unroll
            for (int rg = 0; rg < 4; ++rg)
                C[(size_t)(r0 + rg)*1024 + col] = acc[m][n][rg];
        }
    }
}

// ---------------- qrel via MFMA (verified r10; q pre-scaled -> bias pre-scaled) ----------
__global__ __launch_bounds__(256) void qrel_mfma(const unsigned short* __restrict__ qb,
                                                 const unsigned short* __restrict__ relTb,
                                                 unsigned short* __restrict__ qrelb)
{
    __shared__ __align__(16) unsigned short Rls[8192];   // 128 buckets x 64
    __shared__ __align__(16) unsigned short Qls[8192];   // 128 s-rows  x 64
    const int tid  = threadIdx.x;
    const int wave = tid >> 6, lane = tid & 63;
    const int wr = (wave >> 1) * 64;     // bucket offset
    const int wc = (wave & 1) * 64;      // s offset
    const int s0 = blockIdx.x * 128;
    const int bh = blockIdx.y;
    const int h  = bh & 15;

    const unsigned short* qsrc = qb + ((size_t)bh*2048 + s0)*64;
    const unsigned short* rsrc = relTb + (size_t)h*8192;
#pragma unroll
    for (int j = 0; j < 4; ++j) {
        GLOAD16(rsrc + j*2048 + tid*8, &Rls[0] + j*2048 + tid*8);
        GLOAD16(qsrc + j*2048 + tid*8, &Qls[0] + j*2048 + tid*8);
    }

    f32x4 acc[4][4];
#pragma unroll
    for (int m = 0; m < 4; ++m)
#pragma unroll
        for (int n = 0; n < 4; ++n) acc[m][n] = (f32x4)0.f;

    __syncthreads();

#pragma unroll
    for (int ks = 0; ks < 2; ++ks) {
        bf16x8 rf[4], qf[4];
#pragma unroll
        for (int m = 0; m < 4; ++m)
            rf[m] = *(const bf16x8*)&Rls[(wr + m*16 + (lane & 15))*64 + ks*32 + (lane >> 4)*8];
#pragma unroll
        for (int n = 0; n < 4; ++n)
            qf[n] = *(const bf16x8*)&Qls[(wc + n*16 + (lane & 15))*64 + ks*32 + (lane >> 4)*8];
#pragma unroll
        for (int m = 0; m < 4; ++m)
#pragma unroll
            for (int n = 0; n < 4; ++n)
                acc[m][n] = __builtin_amdgcn_mfma_f32_16x16x32_bf16(rf[m], qf[n], acc[m][n], 0, 0, 0);
    }

#pragma unroll
    for (int m = 0; m < 4; ++m) {
        const int bkt0 = wr + m*16 + (lane >> 4)*4;
#pragma unroll
        for (int n = 0; n < 4; ++n) {
            const int srow = s0 + wc + n*16 + (lane & 15);
            unsigned r01 = cvtpk(acc[m][n][0], acc[m][n][1]);
            unsigned r23 = cvtpk(acc[m][n][2], acc[m][n][3]);
            *(uint2*)(qrelb + ((size_t)bh*2048 + srow)*128 + bkt0) = make_uint2(r01, r23);
        }
    }
}

// ---------------- MFMA causal flash attention: 512 thr / 8 waves / 128 q-rows ----------
// All 8 waves share one K/V tile -> ds_read_b128 per unit work HALVED. qrels pad 138
// (69 words, gcd(69,32)=1) -> gather conflict-free. Bucket arithmetic (no btbl LDS).
// Lower waves (q-rows 0..63) skip the upper diagonal tile. Descending-size dispatch.
__global__ __launch_bounds__(512) void flash_mfma(
    const unsigned short* __restrict__ qb, const unsigned short* __restrict__ kb,
    const unsigned short* __restrict__ vT, const unsigned short* __restrict__ qrelb,
    unsigned short* __restrict__ ctxb)
{
    __shared__ __align__(16) unsigned short kls[2][4096];   // [buf][64 keys x 64 d] swizzled
    __shared__ __align__(16) unsigned short vtls[2][4096];  // [buf][64 d x 64 keys] swizzled
    __shared__ __align__(16) unsigned short qrels[128*138]; // pad 138: conflict-free gather

    const int tid = threadIdx.x;
    const int id  = blockIdx.x;                // 0..511
    const int bh  = id & 31;                   // head -> XCD locality
    const int px  = 15 - (id >> 5);            // descending size: big blocks dispatch first
    const int i0  = px * 128;

    const int w   = tid >> 6;                  // 0..7 -> q-rows w*16..w*16+15 of block's 128
    const int l   = tid & 63;
    const int q15 = l & 15;
    const int g   = l >> 4;
    const int iq  = i0 + w*16 + q15;
    const int tdiag  = 2*px + (w >> 2);        // this wave's diagonal tile
    const int ntiles = 2*px + 2;

    // staging: tid<256 -> K tile (8KB), tid>=256 -> V^T tile (8KB); 2 GLOAD16/thread
    const size_t headoff = (size_t)bh * 2048 * 64;
    const int half = tid >> 8;
    const int t8   = tid & 255;
    const unsigned short* gbase = half ? (vT + headoff) : (kb + headoff);
    const int jstride = half ? 1 : 64;
    int soff[2], doff[2];
#pragma unroll
    for (int i = 0; i < 2; ++i) {
        const int D = t8*16 + i*4096;
        const int r = D >> 7, c = (D >> 4) & 7;
        soff[i] = half ? (r*2048 + ((c ^ (r & 7))*8)) : (r*64 + ((c ^ (r & 7))*8));
        doff[i] = D;
    }

    // stage bias rows (128 q-rows, pad 138 -> u32 writes, 4B-aligned every row)
    for (int idx = tid; idx < 2048; idx += 512) {
        const int r = idx >> 4, c8 = idx & 15;
        uint4 vv = *(const uint4*)(qrelb + ((size_t)bh*2048 + i0 + r)*128 + c8*8);
        unsigned* d = (unsigned*)&qrels[r*138 + c8*8];
        d[0] = vv.x; d[1] = vv.y; d[2] = vv.z; d[3] = vv.w;
    }
    {   // prefetch tile 0 into buf 0
        char* lb = half ? (char*)vtls[0] : (char*)kls[0];
#pragma unroll
        for (int i = 0; i < 2; ++i) GLOAD16(gbase + soff[i], lb + doff[i]);
    }

    bf16x8 qf0, qf1;
    {
        const unsigned short* qrow = qb + ((size_t)bh*2048 + iq)*64;
        qf0 = *(const bf16x8*)(qrow + g*8);
        qf1 = *(const bf16x8*)(qrow + 32 + g*8);
    }

    f32x4 acc[4];
#pragma unroll
    for (int d = 0; d < 4; ++d) acc[d] = (f32x4)0.f;
    float mrun = -INFINITY, lsum = 0.f;

    const int qrow_lds = (w*16 + q15) * 138;
    const int srcA = ((2*g) & 3)*16 + q15;
    const int srcB = ((2*g + 1) & 3)*16 + q15;

    __syncthreads();                        // qrels staged + tile0 drained

    int cur = 0;
    for (int t = 0; t < ntiles; ++t) {
        const int j0 = t * 64;
        if (t + 1 < ntiles) {               // prefetch t+1 into other buf (under compute)
            const unsigned short* gt = gbase + (size_t)(j0 + 64) * jstride;
            char* lb = half ? (char*)vtls[cur ^ 1] : (char*)kls[cur ^ 1];
#pragma unroll
            for (int i = 0; i < 2; ++i) GLOAD16(gt + soff[i], lb + doff[i]);
        }

        if (t <= tdiag) {
            // swapped QK^T: 4 key-subtiles of 16
            f32x4 s[4];
#pragma unroll
            for (int ss = 0; ss < 4; ++ss) s[ss] = (f32x4)0.f;
#pragma unroll
            for (int ks = 0; ks < 2; ++ks) {
                const bf16x8 qq = ks ? qf1 : qf0;
                const int gr = ((ks*4 + g) ^ (q15 & 7)) * 8;
#pragma unroll
                for (int ss = 0; ss < 4; ++ss) {
                    bf16x8 kf = *(const bf16x8*)&kls[cur][(ss*16 + q15)*64 + gr];
                    s[ss] = __builtin_amdgcn_mfma_f32_16x16x32_bf16(kf, qq, s[ss], 0, 0, 0);
                }
            }

            // bias + mask; far tiles (t < tdiag) have rel >= 1: no mask/clamp
            const int relbase = iq - j0 - g*4;
            float sv[16];
            float tmax = -INFINITY;
            if (t != tdiag) {
#pragma unroll
                for (int ss = 0; ss < 4; ++ss) {
#pragma unroll
                    for (int r = 0; r < 4; ++r) {
                        const int bi = relbase - ss*16 - r;
                        int bkt;
                        if (bi < 64) bkt = bi;
                        else {
                            bkt = 64 + (int)(__log2f((float)bi) * 8.0f - 48.0f);
                            bkt = bkt > 127 ? 127 : bkt;
                        }
                        const float bias = bf2f(qrels[qrow_lds + bkt]);
                        const float val = s[ss][r] + bias;
                        sv[ss*4 + r] = val;
                        tmax = fmaxf(tmax, val);
                    }
                }
            } else {
#pragma unroll
                for (int ss = 0; ss < 4; ++ss) {
#pragma unroll
                    for (int r = 0; r < 4; ++r) {
                        const int rel = relbase - ss*16 - r;
                        const int bi = rel < 0 ? 0 : rel;
                        int bkt;
                        if (bi < 64) bkt = bi;
                        else {
                            bkt = 64 + (int)(__log2f((float)bi) * 8.0f - 48.0f);
                            bkt = bkt > 127 ? 127 : bkt;
                        }
                        const float bias = bf2f(qrels[qrow_lds + bkt]);
                        float val = s[ss][r] + bias;
                        val = (rel >= 0) ? val : -1e30f;
                        sv[ss*4 + r] = val;
                        tmax = fmaxf(tmax, val);
                    }
                }
            }
            tmax = fmaxf(tmax, __shfl_xor(tmax, 16));
            tmax = fmaxf(tmax, __shfl_xor(tmax, 32));

            // defer-max: skip rescale when all columns grew <= 8
            float newm = mrun;
            if (!__all(tmax - mrun <= 8.0f)) {
                newm = fmaxf(mrun, tmax);
                const float corr = fexp2(mrun - newm);
                lsum *= corr;
#pragma unroll
                for (int d = 0; d < 4; ++d) {
                    acc[d][0] *= corr; acc[d][1] *= corr; acc[d][2] *= corr; acc[d][3] *= corr;
                }
                mrun = newm;
            }

            float p[16], ps = 0.f;
#pragma unroll
            for (int j = 0; j < 16; ++j) { p[j] = fexp2(sv[j] - newm); ps += p[j]; }
            ps += __shfl_xor(ps, 16);
            ps += __shfl_xor(ps, 32);
            lsum += ps;

            // two 32-key chunks: build P^T B-frag via cvt_pk + shuffles, then PV
#pragma unroll
            for (int ck = 0; ck < 2; ++ck) {
                unsigned w00 = cvtpk(p[8*ck+0], p[8*ck+1]);
                unsigned w01 = cvtpk(p[8*ck+2], p[8*ck+3]);
                unsigned w10 = cvtpk(p[8*ck+4], p[8*ck+5]);
                unsigned w11 = cvtpk(p[8*ck+6], p[8*ck+7]);
                unsigned a0 = (unsigned)__shfl((int)w00, srcA);
                unsigned b0 = (unsigned)__shfl((int)w10, srcA);
                unsigned a1 = (unsigned)__shfl((int)w01, srcA);
                unsigned b1 = (unsigned)__shfl((int)w11, srcA);
                unsigned a2 = (unsigned)__shfl((int)w00, srcB);
                unsigned b2 = (unsigned)__shfl((int)w10, srcB);
                unsigned a3 = (unsigned)__shfl((int)w01, srcB);
                unsigned b3 = (unsigned)__shfl((int)w11, srcB);
                union { unsigned u[4]; bf16x8 v; } pu;
                pu.u[0] = (g < 2) ? a0 : b0;
                pu.u[1] = (g < 2) ? a1 : b1;
                pu.u[2] = (g < 2) ? a2 : b2;
                pu.u[3] = (g < 2) ? a3 : b3;
#pragma unroll
                for (int dblk = 0; dblk < 4; ++dblk) {
                    const int d2 = dblk*16 + q15;
                    bf16x8 vf = *(const bf16x8*)&vtls[cur][d2*64 + (((ck*4 + g) ^ (d2 & 7))*8)];
                    acc[dblk] = __builtin_amdgcn_mfma_f32_16x16x32_bf16(vf, pu.v, acc[dblk], 0, 0, 0);
                }
            }
        }

        __syncthreads();                    // drains t+1 loads; all waves done with buf cur
        cur ^= 1;
    }

    const float inv = 1.0f / lsum;
    const int s2 = iq;
    const int b2 = bh >> 4, hh = bh & 15;
    unsigned short* obase = ctxb + (((size_t)b2*2048 + s2)*16 + hh)*64;
#pragma unroll
    for (int dblk = 0; dblk < 4; ++dblk) {
        const int d0 = dblk*16 + g*4;
        unsigned r01 = cvtpk(acc[dblk][0]*inv, acc[dblk][1]*inv);
        unsigned r23 = cvtpk(acc[dblk][2]*inv, acc[dblk][3]*inv);
        *(uint2*)(obase + d0) = make_uint2(r01, r23);
    }
}

extern "C" void kernel_launch(void* const* d_in, const int* in_sizes, int n_in,
                              void* d_out, int out_size, void* d_ws, size_t ws_size,
                              hipStream_t stream)
{
    const float* x   = (const float*)d_in[0];
    const float* Wq  = (const float*)d_in[1];
    const float* Wk  = (const float*)d_in[2];
    const float* Wv  = (const float*)d_in[3];
    const float* Wo  = (const float*)d_in[4];
    const float* rel = (const float*)d_in[5];

    float* ws = (float*)d_ws;
    unsigned short* qb    = (unsigned short*)(ws + 8388608);    // 4,194,304 bf16
    unsigned short* kbb   = (unsigned short*)(ws + 10485760);   // 4,194,304 bf16
    unsigned short* qrelb = (unsigned short*)(ws + 12582912);   // 8,388,608 bf16 (4M floats)
    unsigned short* vTb   = (unsigned short*)(ws + 16777216);   // 4,194,304 bf16
    unsigned short* xb    = (unsigned short*)(ws + 18874368);   // 4,194,304 bf16
    unsigned short* wtq   = (unsigned short*)(ws + 20971520);   // 1,048,576 bf16 each
    unsigned short* wtk   = (unsigned short*)(ws + 21495808);
    unsigned short* wtv   = (unsigned short*)(ws + 22020096);
    unsigned short* wto   = (unsigned short*)(ws + 22544384);
    unsigned short* relTb = (unsigned short*)(ws + 23068672);   // 131,072 bf16 -> ends 23134208
    float*          ropeT = ws + 23134208;                      // 131,072 f32 -> ends 23265280
    unsigned short* ctxb  = (unsigned short*)ws;                // first region (free)

    prep<<<3264, 256, 0, stream>>>(x, Wq, Wk, Wv, Wo, rel, xb, wtq, wtk, wtv, wto, relTb, ropeT);
    gemm_qkv<<<dim3(8, 32, 3), 256, 0, stream>>>(xb, wtq, wtk, wtv, ropeT, qb, kbb, vTb);
    qrel_mfma<<<dim3(16, 32), 256, 0, stream>>>(qb, relTb, qrelb);
    flash_mfma<<<512, 512, 0, stream>>>(qb, kbb, vTb, qrelb, ctxb);
    gemm_o<<<dim3(8, 32), 256, 0, stream>>>(ctxb, wto, (float*)d_out);
}